// Round 6
// baseline (444.063 us; speedup 1.0000x reference)
//
#include <hip/hip_runtime.h>

typedef __attribute__((ext_vector_type(8))) short short8v;
typedef __attribute__((ext_vector_type(4))) float float4v;
typedef __attribute__((ext_vector_type(2))) unsigned int u32x2;
typedef __attribute__((ext_vector_type(4))) unsigned int u32x4;
typedef unsigned short u16;
typedef unsigned int u32;
typedef const __attribute__((address_space(1))) void* gas1;
typedef __attribute__((address_space(3))) void* las3;

#define NN 4096
#define EE 32768
#define DI 128
#define DO 128

__device__ __forceinline__ u16 f2bf(float f) {
    u32 u = __builtin_bit_cast(u32, f);
    u32 r = u + 0x7fffu + ((u >> 16) & 1u);   // round-to-nearest-even
    return (u16)(r >> 16);
}
__device__ __forceinline__ u32 pack2bf(float lo, float hi) {
    return (u32)f2bf(lo) | ((u32)f2bf(hi) << 16);
}
__device__ __forceinline__ void gload16(const void* g, void* l) {
    __builtin_amdgcn_global_load_lds((gas1)g, (las3)l, 16, 0, 0);
}
__device__ __forceinline__ u32 cvtpk(float lo, float hi) {
    u32 r;
    asm("v_cvt_pk_bf16_f32 %0, %1, %2" : "=v"(r) : "v"(lo), "v"(hi));
    return r;
}

// ---- helpers used by k1 only ----
template<int R, int C>
__device__ __forceinline__ void stage_f32_bf16(char* lds, const float* src, int ld) {
    constexpr int CH = C / 8;
    constexpr int ITER = (R * CH) / 256;
#pragma unroll
    for (int it = 0; it < ITER; ++it) {
        int c = it * 256 + (int)threadIdx.x;
        int row = c / CH, col8 = c % CH;
        const float* p = src + (size_t)row * ld + col8 * 8;
        float4v v0 = *(const float4v*)p;
        float4v v1 = *(const float4v*)(p + 4);
        u32x4 w;
        w[0] = pack2bf(v0[0], v0[1]);
        w[1] = pack2bf(v0[2], v0[3]);
        w[2] = pack2bf(v1[0], v1[1]);
        w[3] = pack2bf(v1[2], v1[3]);
        int kb = col8 * 16;
        *(u32x4*)(lds + row * (C * 2) + (kb ^ ((row & 7) << 4))) = w;
    }
}
template<int ROWB>
__device__ __forceinline__ short8v ldfrag(const char* base, int row16, int kk) {
    int l = (int)threadIdx.x & 63;
    int row = row16 + (l & 15);
    int kb = kk * 64 + ((l >> 4) << 4);
    return *(const short8v*)(base + row * ROWB + (kb ^ ((row & 7) << 4)));
}

// ---------- kernel 1: ATB[mo][n] = sum_i f_w[o][m*128+i] * x[n][i]  (mo = m*128+o) ----------
__global__ __launch_bounds__(256) void k1_ab(const float* __restrict__ x,
                                             const float* __restrict__ fw,
                                             u16* __restrict__ ATB) {
    __shared__ __align__(16) char lds[64 * 1024];
    char* aL = lds;              // [128 mo][128 i], ROWB 256
    char* bL = lds + 32 * 1024;  // [128 n][128 i]
    int mb = (int)blockIdx.x >> 5, nb = (int)blockIdx.x & 31;
    stage_f32_bf16<128, 128>(aL, fw + mb * 128, 2 * DI);
    stage_f32_bf16<128, 128>(bL, x + (size_t)nb * 128 * DI, DI);
    __syncthreads();
    int w = (int)threadIdx.x >> 6, l = (int)threadIdx.x & 63;
    int wr = w >> 1, wc = w & 1;
    float4v acc[4][4] = {};
#pragma unroll
    for (int kk = 0; kk < 4; ++kk) {
        short8v af[4], bf[4];
#pragma unroll
        for (int m = 0; m < 4; ++m) af[m] = ldfrag<256>(aL, wr * 64 + m * 16, kk);
#pragma unroll
        for (int n2 = 0; n2 < 4; ++n2) bf[n2] = ldfrag<256>(bL, wc * 64 + n2 * 16, kk);
#pragma unroll
        for (int m = 0; m < 4; ++m)
#pragma unroll
            for (int n2 = 0; n2 < 4; ++n2)
                acc[m][n2] = __builtin_amdgcn_mfma_f32_16x16x32_bf16(af[m], bf[n2], acc[m][n2], 0, 0, 0);
    }
#pragma unroll
    for (int m = 0; m < 4; ++m)
#pragma unroll
        for (int n2 = 0; n2 < 4; ++n2)
#pragma unroll
            for (int r = 0; r < 4; ++r) {
                int mo = mb * 128 + wr * 64 + m * 16 + ((l >> 4) << 2) + r;
                int n  = nb * 128 + wc * 64 + n2 * 16 + (l & 15);
                ATB[(size_t)mo * NN + n] = f2bf(acc[m][n2][r]);
            }
}

// ---------- kernel 2: YT[o][e] = relu(sum_mat sum_n ATB[mat][o][n]*M[n][e] + fb[o]) ----------
// grid 1024 e-tiles of 32. 128 K-steps (64 src + 64 tgt), acc carried across phases.
// LDS 40KB -> 4 blocks/CU. ATB: gload_lds dbuf (own-wave rows).
// M: global->reg->cvtpk->transposed bf16 LDS dbuf. Counted vmcnt(6)/(4) — never 0.
__global__ __launch_bounds__(256, 4) void k2_y(const float* __restrict__ src,
                                               const float* __restrict__ tgt,
                                               const u16* __restrict__ ATB,
                                               const float* __restrict__ fb,
                                               u16* __restrict__ YT) {
    __shared__ __align__(16) char lds[40 * 1024]; // ATB bufs @0,16K; Mt bufs @32K,36K
    const int eb = (int)blockIdx.x * 32;
    const int t = (int)threadIdx.x, w = t >> 6, l = t & 63;
    const int eq = t & 7, np = t >> 3;            // 8 e-quads x 32 n-pairs

    float4v r0, r1;
    auto loadT = [&](int ks) {                    // M[n0+2np..+1][eb+eq*4..+3] -> regs
        const float* M = (ks >= 64 ? tgt : src);
        const int n0 = (ks & 63) * 64;
        const float* p = M + (size_t)(n0 + 2 * np) * EE + eb + eq * 4;
        r0 = *(const float4v*)p;
        r1 = *(const float4v*)(p + EE);
    };
    auto gloadA = [&](int ks, int p) {            // ATB tile [128 o][64 n] bf16, pre-swz src
        const int mat = ks >> 6, n0 = (ks & 63) * 64;
        const u16* AB = ATB + (size_t)mat * 128 * NN + n0;
#pragma unroll
        for (int q = 0; q < 4; ++q) {
            const int s = w * 4 + q;
            const int r = s * 8 + (l >> 3);
            const u16* ga = AB + (size_t)r * NN + (((l & 7) ^ (r & 7)) << 3);
            gload16(ga, lds + p * 16384 + s * 1024);
        }
    };
    auto writeT = [&](int p) {                    // regs -> Mt [32 e][64 n] bf16, XOR-swz
        char* buf = lds + 32768 + p * 4096;
#pragma unroll
        for (int j = 0; j < 4; ++j) {
            int e = eq * 4 + j;
            *(u32*)(buf + e * 128 + ((np * 4) ^ ((e & 7) << 4))) = cvtpk(r0[j], r1[j]);
        }
    };

    loadT(0);
    gloadA(0, 0);
    writeT(0);
    __syncthreads();   // prologue only (drains once; Mt(0)+ATB(0) visible)

    float4v acc[2][2] = {};
    for (int ks = 0; ks < 128; ++ks) {
        const int nx = ks < 127 ? ks + 1 : 127;   // last-step dup keeps vmcnt counts exact
        loadT(nx);                                 // 2 reg loads (issued FIRST)
        gloadA(nx, (ks + 1) & 1);                  // 4 gload_lds
        asm volatile("s_waitcnt vmcnt(6)" ::: "memory");   // ATB(ks) landed; 6 in flight
        __builtin_amdgcn_sched_barrier(0);
        const char* bufA = lds + (ks & 1) * 16384;
        const char* bufB = lds + 32768 + (ks & 1) * 4096;
        short8v af[2][2], bfr[2][2];
#pragma unroll
        for (int kk = 0; kk < 2; ++kk) {
#pragma unroll
            for (int m = 0; m < 2; ++m)
                af[kk][m] = ldfrag<128>(bufA, w * 32 + m * 16, kk);
#pragma unroll
            for (int n2 = 0; n2 < 2; ++n2)
                bfr[kk][n2] = ldfrag<128>(bufB, n2 * 16, kk);
        }
#pragma unroll
        for (int kk = 0; kk < 2; ++kk)
#pragma unroll
            for (int m = 0; m < 2; ++m)
#pragma unroll
                for (int n2 = 0; n2 < 2; ++n2)
                    acc[m][n2] = __builtin_amdgcn_mfma_f32_16x16x32_bf16(
                        af[kk][m], bfr[kk][n2], acc[m][n2], 0, 0, 0);
        asm volatile("s_waitcnt vmcnt(4)" ::: "memory");   // loadT(ks+1) regs ready
        __builtin_amdgcn_sched_barrier(0);
        writeT((ks + 1) & 1);
        asm volatile("s_waitcnt lgkmcnt(0)" ::: "memory"); // ds_writes visible
        __builtin_amdgcn_sched_barrier(0);
        __builtin_amdgcn_s_barrier();
    }
#pragma unroll
    for (int m = 0; m < 2; ++m)
#pragma unroll
        for (int n2 = 0; n2 < 2; ++n2)
#pragma unroll
            for (int r = 0; r < 4; ++r) {
                const int o = w * 32 + m * 16 + ((l >> 4) << 2) + r;
                const int e = eb + n2 * 16 + (l & 15);
                float v = acc[m][n2][r] + fb[o];
                v = v > 0.f ? v : 0.f;
                YT[(size_t)o * EE + e] = f2bf(v);
            }
}

// ---------- kernel 3: part[kc][n][o] = sum_{e in chunk kc} tgt[n][e] * YT[o][e] ----------
// grid 1024 = 64 mb x 16 kc. LDS 48KB -> 3 blocks/CU.
// T: global->reg->cvtpk->bf16 LDS dbuf [64 n][64 e]. Y: gload_lds dbuf.
__global__ __launch_bounds__(256, 3) void k3_part(const float* __restrict__ tgt,
                                                  const u16* __restrict__ YT,
                                                  float* __restrict__ part) {
    __shared__ __align__(16) char lds[48 * 1024]; // T bufs @0,8K (bf16); Y bufs @16K,32K
    const int bid = (int)blockIdx.x;
    const int mb = bid & 63, kc = bid >> 6;
    const int e0 = kc * 2048;
    const int t = (int)threadIdx.x, w = t >> 6, l = t & 63;
    const int wr = w >> 1, wc = w & 1;
    const int trow = t >> 2, te0 = (t & 3) * 16;  // 64 rows x 4 col-chunks of 16 e

    float4v v0, v1, v2, v3;
    auto loadT = [&](int es) {                    // tgt[mb*64+trow][ec+te0..+15] -> regs
        const float* p = tgt + (size_t)(mb * 64 + trow) * EE + e0 + es * 64 + te0;
        v0 = *(const float4v*)p;
        v1 = *(const float4v*)(p + 4);
        v2 = *(const float4v*)(p + 8);
        v3 = *(const float4v*)(p + 12);
    };
    auto gloadY = [&](int es, int p) {            // Y tile [128 o][64 e] bf16, pre-swz src
        const int ec = e0 + es * 64;
#pragma unroll
        for (int q = 0; q < 4; ++q) {
            const int s = w * 4 + q;
            const int r = s * 8 + (l >> 3);
            const u16* gy = YT + (size_t)r * EE + ec + (((l & 7) ^ (r & 7)) << 3);
            gload16(gy, lds + 16384 + p * 16384 + s * 1024);
        }
    };
    auto writeT = [&](int p) {                    // regs -> T [64 n][64 e] bf16, XOR-swz
        char* buf = lds + p * 8192;
        u32x4 wA, wB;
        wA[0] = cvtpk(v0[0], v0[1]); wA[1] = cvtpk(v0[2], v0[3]);
        wA[2] = cvtpk(v1[0], v1[1]); wA[3] = cvtpk(v1[2], v1[3]);
        wB[0] = cvtpk(v2[0], v2[1]); wB[1] = cvtpk(v2[2], v2[3]);
        wB[2] = cvtpk(v3[0], v3[1]); wB[3] = cvtpk(v3[2], v3[3]);
        *(u32x4*)(buf + trow * 128 + ((te0 * 2) ^ ((trow & 7) << 4))) = wA;
        *(u32x4*)(buf + trow * 128 + ((te0 * 2 + 16) ^ ((trow & 7) << 4))) = wB;
    };

    loadT(0);
    gloadY(0, 0);
    writeT(0);
    __syncthreads();   // prologue only

    float4v acc[2][4] = {};
    for (int es = 0; es < 32; ++es) {
        const int nx = es < 31 ? es + 1 : 31;
        loadT(nx);                                 // 4 reg loads (FIRST)
        gloadY(nx, (es + 1) & 1);                  // 4 gload_lds
        asm volatile("s_waitcnt vmcnt(8)" ::: "memory");   // Y(es) landed (own wave)
        __builtin_amdgcn_sched_barrier(0);
        __builtin_amdgcn_s_barrier();              // all waves' Y(es) landed (cross-wave reads)
        const char* bufT = lds + (es & 1) * 8192;
        const char* bufY = lds + 16384 + (es & 1) * 16384;
        short8v af[2][2], bfr[2][4];
#pragma unroll
        for (int kk = 0; kk < 2; ++kk) {
#pragma unroll
            for (int m = 0; m < 2; ++m)
                af[kk][m] = ldfrag<128>(bufT, wr * 32 + m * 16, kk);
#pragma unroll
            for (int n2 = 0; n2 < 4; ++n2)
                bfr[kk][n2] = ldfrag<128>(bufY, wc * 64 + n2 * 16, kk);
        }
#pragma unroll
        for (int kk = 0; kk < 2; ++kk)
#pragma unroll
            for (int m = 0; m < 2; ++m)
#pragma unroll
                for (int n2 = 0; n2 < 4; ++n2)
                    acc[m][n2] = __builtin_amdgcn_mfma_f32_16x16x32_bf16(
                        af[kk][m], bfr[kk][n2], acc[m][n2], 0, 0, 0);
        asm volatile("s_waitcnt vmcnt(4)" ::: "memory");   // loadT(es+1) regs ready
        __builtin_amdgcn_sched_barrier(0);
        writeT((es + 1) & 1);
        asm volatile("s_waitcnt lgkmcnt(0)" ::: "memory");
        __builtin_amdgcn_sched_barrier(0);
        __builtin_amdgcn_s_barrier();              // T(es+1) published
    }
#pragma unroll
    for (int m = 0; m < 2; ++m)
#pragma unroll
        for (int n2 = 0; n2 < 4; ++n2)
#pragma unroll
            for (int r = 0; r < 4; ++r) {
                const int n = mb * 64 + wr * 32 + m * 16 + ((l >> 4) << 2) + r;
                const int o = wc * 64 + n2 * 16 + (l & 15);
                part[((size_t)kc * NN + n) * DO + o] = acc[m][n2][r];
            }
}

// ---------- kernel 4: out = sum_kc part[kc] ----------
__global__ __launch_bounds__(256) void k4_red(const float* __restrict__ part,
                                              float* __restrict__ out) {
    size_t i = ((size_t)blockIdx.x * 256 + threadIdx.x) * 4;
    float4v s = {0.f, 0.f, 0.f, 0.f};
#pragma unroll
    for (int kc = 0; kc < 16; ++kc)
        s += *(const float4v*)(part + (size_t)kc * NN * DO + i);
    *(float4v*)(out + i) = s;
}

extern "C" void kernel_launch(void* const* d_in, const int* in_sizes, int n_in,
                              void* d_out, int out_size, void* d_ws, size_t ws_size,
                              hipStream_t stream) {
    const float* x   = (const float*)d_in[0];
    const float* src = (const float*)d_in[1];
    const float* tgt = (const float*)d_in[2];
    const float* fw  = (const float*)d_in[3];
    const float* fb  = (const float*)d_in[4];
    float* out = (float*)d_out;

    char* ws = (char*)d_ws;
    u16*   ATB  = (u16*)ws;                                  //  2 MB: [256][4096] bf16
    u16*   YT   = (u16*)(ws + (size_t)2 * 1024 * 1024);      //  8 MB: [128][32768] bf16
    float* PART = (float*)(ws + (size_t)16 * 1024 * 1024);   // 32 MB: [16][4096][128] f32

    k1_ab  <<<64,   256, 0, stream>>>(x, fw, ATB);
    k2_y   <<<1024, 256, 0, stream>>>(src, tgt, ATB, fb, YT);
    k3_part<<<1024, 256, 0, stream>>>(tgt, YT, PART);
    k4_red <<<512,  256, 0, stream>>>(PART, out);
}

// Round 7
// 374.319 us; speedup vs baseline: 1.1863x; 1.1863x over previous
//
#include <hip/hip_runtime.h>

typedef __attribute__((ext_vector_type(8))) short short8v;
typedef __attribute__((ext_vector_type(4))) float float4v;
typedef __attribute__((ext_vector_type(2))) unsigned int u32x2;
typedef __attribute__((ext_vector_type(4))) unsigned int u32x4;
typedef unsigned short u16;
typedef unsigned int u32;
typedef const __attribute__((address_space(1))) void* gas1;
typedef __attribute__((address_space(3))) void* las3;

#define NN 4096
#define EE 32768
#define DI 128
#define DO 128

__device__ __forceinline__ u16 f2bf(float f) {
    u32 u = __builtin_bit_cast(u32, f);
    u32 r = u + 0x7fffu + ((u >> 16) & 1u);   // round-to-nearest-even
    return (u16)(r >> 16);
}
__device__ __forceinline__ u32 pack2bf(float lo, float hi) {
    return (u32)f2bf(lo) | ((u32)f2bf(hi) << 16);
}
__device__ __forceinline__ void gload16(const void* g, void* l) {
    __builtin_amdgcn_global_load_lds((gas1)g, (las3)l, 16, 0, 0);
}
__device__ __forceinline__ u32 cvtpk(float lo, float hi) {
    u32 r;
    asm("v_cvt_pk_bf16_f32 %0, %1, %2" : "=v"(r) : "v"(lo), "v"(hi));
    return r;
}

// ---- helpers used by k1 only ----
template<int R, int C>
__device__ __forceinline__ void stage_f32_bf16(char* lds, const float* src, int ld) {
    constexpr int CH = C / 8;
    constexpr int ITER = (R * CH) / 256;
#pragma unroll
    for (int it = 0; it < ITER; ++it) {
        int c = it * 256 + (int)threadIdx.x;
        int row = c / CH, col8 = c % CH;
        const float* p = src + (size_t)row * ld + col8 * 8;
        float4v v0 = *(const float4v*)p;
        float4v v1 = *(const float4v*)(p + 4);
        u32x4 w;
        w[0] = pack2bf(v0[0], v0[1]);
        w[1] = pack2bf(v0[2], v0[3]);
        w[2] = pack2bf(v1[0], v1[1]);
        w[3] = pack2bf(v1[2], v1[3]);
        int kb = col8 * 16;
        *(u32x4*)(lds + row * (C * 2) + (kb ^ ((row & 7) << 4))) = w;
    }
}
template<int ROWB>
__device__ __forceinline__ short8v ldfrag(const char* base, int row16, int kk) {
    int l = (int)threadIdx.x & 63;
    int row = row16 + (l & 15);
    int kb = kk * 64 + ((l >> 4) << 4);
    return *(const short8v*)(base + row * ROWB + (kb ^ ((row & 7) << 4)));
}

// ---------- kernel 1: ATB[mo][n] = sum_i f_w[o][m*128+i] * x[n][i]  (mo = m*128+o) ----------
__global__ __launch_bounds__(256) void k1_ab(const float* __restrict__ x,
                                             const float* __restrict__ fw,
                                             u16* __restrict__ ATB) {
    __shared__ __align__(16) char lds[64 * 1024];
    char* aL = lds;              // [128 mo][128 i], ROWB 256
    char* bL = lds + 32 * 1024;  // [128 n][128 i]
    int mb = (int)blockIdx.x >> 5, nb = (int)blockIdx.x & 31;
    stage_f32_bf16<128, 128>(aL, fw + mb * 128, 2 * DI);
    stage_f32_bf16<128, 128>(bL, x + (size_t)nb * 128 * DI, DI);
    __syncthreads();
    int w = (int)threadIdx.x >> 6, l = (int)threadIdx.x & 63;
    int wr = w >> 1, wc = w & 1;
    float4v acc[4][4] = {};
#pragma unroll
    for (int kk = 0; kk < 4; ++kk) {
        short8v af[4], bf[4];
#pragma unroll
        for (int m = 0; m < 4; ++m) af[m] = ldfrag<256>(aL, wr * 64 + m * 16, kk);
#pragma unroll
        for (int n2 = 0; n2 < 4; ++n2) bf[n2] = ldfrag<256>(bL, wc * 64 + n2 * 16, kk);
#pragma unroll
        for (int m = 0; m < 4; ++m)
#pragma unroll
            for (int n2 = 0; n2 < 4; ++n2)
                acc[m][n2] = __builtin_amdgcn_mfma_f32_16x16x32_bf16(af[m], bf[n2], acc[m][n2], 0, 0, 0);
    }
#pragma unroll
    for (int m = 0; m < 4; ++m)
#pragma unroll
        for (int n2 = 0; n2 < 4; ++n2)
#pragma unroll
            for (int r = 0; r < 4; ++r) {
                int mo = mb * 128 + wr * 64 + m * 16 + ((l >> 4) << 2) + r;
                int n  = nb * 128 + wc * 64 + n2 * 16 + (l & 15);
                ATB[(size_t)mo * NN + n] = f2bf(acc[m][n2][r]);
            }
}

// ---------- kernel 2: YT[o][e] = relu(sum_mat sum_n ATB[mat][o][n]*M[n][e] + fb[o]) ----------
// grid 512 e-tiles of 64. 128 K-steps (64 src + 64 tgt), acc carried across phases.
// 2-DEEP reg prefetch: loadT(ks+2) issued at step ks; writeT consumes tile ks+1 loaded
// a full step earlier. Single vmcnt(8)+lgkmcnt(0)+s_barrier per step — no same-step dep.
__global__ __launch_bounds__(256, 3) void k2_y(const float* __restrict__ src,
                                               const float* __restrict__ tgt,
                                               const u16* __restrict__ ATB,
                                               const float* __restrict__ fb,
                                               u16* __restrict__ YT) {
    __shared__ __align__(16) char lds[48 * 1024]; // ATB bufs @0,16K; Mt bufs @32K,40K
    const int eb = (int)blockIdx.x * 64;
    const int t = (int)threadIdx.x, w = t >> 6, l = t & 63;
    const int eq = t & 15, nq = t >> 4;           // 16 e-quads x 16 n-quads

    auto loadT = [&](int ks, float4v& r0, float4v& r1, float4v& r2, float4v& r3) {
        const float* M = (ks >= 64 ? tgt : src);
        const int n0 = (ks & 63) * 64;
        const float* p = M + (size_t)(n0 + nq * 4) * EE + eb + eq * 4;
        r0 = *(const float4v*)p;
        r1 = *(const float4v*)(p + EE);
        r2 = *(const float4v*)(p + 2 * EE);
        r3 = *(const float4v*)(p + 3 * EE);
    };
    auto gloadA = [&](int ks, int p) {            // ATB tile [128 o][64 n] bf16, pre-swz src
        const int mat = ks >> 6, n0 = (ks & 63) * 64;
        const u16* AB = ATB + (size_t)mat * 128 * NN + n0;
#pragma unroll
        for (int q = 0; q < 4; ++q) {
            const int s = w * 4 + q;
            const int r = s * 8 + (l >> 3);
            const u16* ga = AB + (size_t)r * NN + (((l & 7) ^ (r & 7)) << 3);
            gload16(ga, lds + p * 16384 + s * 1024);
        }
    };
    auto writeT = [&](int p, float4v& r0, float4v& r1, float4v& r2, float4v& r3) {
        char* buf = lds + 32768 + p * 8192;       // Mt [64 e][64 n] bf16, XOR-swz
#pragma unroll
        for (int j = 0; j < 4; ++j) {
            int e = eq * 4 + j;
            u32x2 w2;
            w2[0] = cvtpk(r0[j], r1[j]);
            w2[1] = cvtpk(r2[j], r3[j]);
            *(u32x2*)(buf + e * 128 + ((nq * 8) ^ ((e & 7) << 4))) = w2;
        }
    };

    float4v acc[2][4] = {};
    // step: tile ks from LDS; issue loadT(ks+2)->cur regs; writeT(next regs = tile ks+1)
    auto step = [&](int ks, float4v& c0, float4v& c1, float4v& c2, float4v& c3,
                    float4v& x0, float4v& x1, float4v& x2, float4v& x3) {
        const int nx2 = ks + 2 < 128 ? ks + 2 : 127;
        const int nx1 = ks + 1 < 128 ? ks + 1 : 127;
        loadT(nx2, c0, c1, c2, c3);                // 4 reg loads (full-step slack)
        gloadA(nx1, (ks + 1) & 1);                 // 4 gload_lds  (full-step slack)
        asm volatile("s_waitcnt vmcnt(8)" ::: "memory");  // loadT(ks+1)+gloadA(ks) landed
        __builtin_amdgcn_sched_barrier(0);
        const char* bufA = lds + (ks & 1) * 16384;
        const char* bufB = lds + 32768 + (ks & 1) * 8192;
        short8v af[2][2], bfr[2][4];
#pragma unroll
        for (int kk = 0; kk < 2; ++kk) {
#pragma unroll
            for (int m = 0; m < 2; ++m)
                af[kk][m] = ldfrag<128>(bufA, w * 32 + m * 16, kk);
#pragma unroll
            for (int n2 = 0; n2 < 4; ++n2)
                bfr[kk][n2] = ldfrag<128>(bufB, n2 * 16, kk);
        }
#pragma unroll
        for (int kk = 0; kk < 2; ++kk)
#pragma unroll
            for (int m = 0; m < 2; ++m)
#pragma unroll
                for (int n2 = 0; n2 < 4; ++n2)
                    acc[m][n2] = __builtin_amdgcn_mfma_f32_16x16x32_bf16(
                        af[kk][m], bfr[kk][n2], acc[m][n2], 0, 0, 0);
        writeT((ks + 1) & 1, x0, x1, x2, x3);      // tile ks+1 -> Mt buf, regs already ready
        asm volatile("s_waitcnt lgkmcnt(0)" ::: "memory");
        __builtin_amdgcn_sched_barrier(0);
        __builtin_amdgcn_s_barrier();
    };

    float4v a0, a1, a2, a3, b0, b1, b2, b3;       // two named reg sets (static indexing)
    loadT(0, a0, a1, a2, a3);
    asm volatile("s_waitcnt vmcnt(0)" ::: "memory");   // prologue-only drain
    writeT(0, a0, a1, a2, a3);
    loadT(1, b0, b1, b2, b3);
    gloadA(0, 0);
    __syncthreads();                               // prologue-only full drain

    for (int ks = 0; ks < 128; ks += 2) {
        step(ks,     a0, a1, a2, a3,  b0, b1, b2, b3);  // refill a<-tile ks+2, write b=tile ks+1
        step(ks + 1, b0, b1, b2, b3,  a0, a1, a2, a3);  // refill b<-tile ks+3, write a=tile ks+2
    }
#pragma unroll
    for (int m = 0; m < 2; ++m)
#pragma unroll
        for (int n2 = 0; n2 < 4; ++n2)
#pragma unroll
            for (int r = 0; r < 4; ++r) {
                const int o = w * 32 + m * 16 + ((l >> 4) << 2) + r;
                const int e = eb + n2 * 16 + (l & 15);
                float v = acc[m][n2][r] + fb[o];
                v = v > 0.f ? v : 0.f;
                YT[(size_t)o * EE + e] = f2bf(v);
            }
}

// ---------- kernel 3: part[kc][n][o] = sum_{e in chunk kc} tgt[n][e] * YT[o][e] ----------
// grid 1024 = 64 mb x 16 kc. LDS 48KB -> 3 blocks/CU. (unchanged from R6 — near floor)
__global__ __launch_bounds__(256, 3) void k3_part(const float* __restrict__ tgt,
                                                  const u16* __restrict__ YT,
                                                  float* __restrict__ part) {
    __shared__ __align__(16) char lds[48 * 1024]; // T bufs @0,8K (bf16); Y bufs @16K,32K
    const int bid = (int)blockIdx.x;
    const int mb = bid & 63, kc = bid >> 6;
    const int e0 = kc * 2048;
    const int t = (int)threadIdx.x, w = t >> 6, l = t & 63;
    const int wr = w >> 1, wc = w & 1;
    const int trow = t >> 2, te0 = (t & 3) * 16;  // 64 rows x 4 col-chunks of 16 e

    float4v v0, v1, v2, v3;
    auto loadT = [&](int es) {                    // tgt[mb*64+trow][ec+te0..+15] -> regs
        const float* p = tgt + (size_t)(mb * 64 + trow) * EE + e0 + es * 64 + te0;
        v0 = *(const float4v*)p;
        v1 = *(const float4v*)(p + 4);
        v2 = *(const float4v*)(p + 8);
        v3 = *(const float4v*)(p + 12);
    };
    auto gloadY = [&](int es, int p) {            // Y tile [128 o][64 e] bf16, pre-swz src
        const int ec = e0 + es * 64;
#pragma unroll
        for (int q = 0; q < 4; ++q) {
            const int s = w * 4 + q;
            const int r = s * 8 + (l >> 3);
            const u16* gy = YT + (size_t)r * EE + ec + (((l & 7) ^ (r & 7)) << 3);
            gload16(gy, lds + 16384 + p * 16384 + s * 1024);
        }
    };
    auto writeT = [&](int p) {                    // regs -> T [64 n][64 e] bf16, XOR-swz
        char* buf = lds + p * 8192;
        u32x4 wA, wB;
        wA[0] = cvtpk(v0[0], v0[1]); wA[1] = cvtpk(v0[2], v0[3]);
        wA[2] = cvtpk(v1[0], v1[1]); wA[3] = cvtpk(v1[2], v1[3]);
        wB[0] = cvtpk(v2[0], v2[1]); wB[1] = cvtpk(v2[2], v2[3]);
        wB[2] = cvtpk(v3[0], v3[1]); wB[3] = cvtpk(v3[2], v3[3]);
        *(u32x4*)(buf + trow * 128 + ((te0 * 2) ^ ((trow & 7) << 4))) = wA;
        *(u32x4*)(buf + trow * 128 + ((te0 * 2 + 16) ^ ((trow & 7) << 4))) = wB;
    };

    loadT(0);
    gloadY(0, 0);
    writeT(0);
    __syncthreads();   // prologue only

    float4v acc[2][4] = {};
    for (int es = 0; es < 32; ++es) {
        const int nx = es < 31 ? es + 1 : 31;
        loadT(nx);                                 // 4 reg loads (FIRST)
        gloadY(nx, (es + 1) & 1);                  // 4 gload_lds
        asm volatile("s_waitcnt vmcnt(8)" ::: "memory");   // Y(es) landed (own wave)
        __builtin_amdgcn_sched_barrier(0);
        __builtin_amdgcn_s_barrier();              // all waves' Y(es) landed (cross-wave reads)
        const char* bufT = lds + (es & 1) * 8192;
        const char* bufY = lds + 16384 + (es & 1) * 16384;
        short8v af[2][2], bfr[2][4];
#pragma unroll
        for (int kk = 0; kk < 2; ++kk) {
#pragma unroll
            for (int m = 0; m < 2; ++m)
                af[kk][m] = ldfrag<128>(bufT, wr * 32 + m * 16, kk);
#pragma unroll
            for (int n2 = 0; n2 < 4; ++n2)
                bfr[kk][n2] = ldfrag<128>(bufY, wc * 64 + n2 * 16, kk);
        }
#pragma unroll
        for (int kk = 0; kk < 2; ++kk)
#pragma unroll
            for (int m = 0; m < 2; ++m)
#pragma unroll
                for (int n2 = 0; n2 < 4; ++n2)
                    acc[m][n2] = __builtin_amdgcn_mfma_f32_16x16x32_bf16(
                        af[kk][m], bfr[kk][n2], acc[m][n2], 0, 0, 0);
        asm volatile("s_waitcnt vmcnt(4)" ::: "memory");   // loadT(es+1) regs ready
        __builtin_amdgcn_sched_barrier(0);
        writeT((es + 1) & 1);
        asm volatile("s_waitcnt lgkmcnt(0)" ::: "memory");
        __builtin_amdgcn_sched_barrier(0);
        __builtin_amdgcn_s_barrier();              // T(es+1) published
    }
#pragma unroll
    for (int m = 0; m < 2; ++m)
#pragma unroll
        for (int n2 = 0; n2 < 4; ++n2)
#pragma unroll
            for (int r = 0; r < 4; ++r) {
                const int n = mb * 64 + wr * 32 + m * 16 + ((l >> 4) << 2) + r;
                const int o = wc * 64 + n2 * 16 + (l & 15);
                part[((size_t)kc * NN + n) * DO + o] = acc[m][n2][r];
            }
}

// ---------- kernel 4: out = sum_kc part[kc] ----------
__global__ __launch_bounds__(256) void k4_red(const float* __restrict__ part,
                                              float* __restrict__ out) {
    size_t i = ((size_t)blockIdx.x * 256 + threadIdx.x) * 4;
    float4v s = {0.f, 0.f, 0.f, 0.f};
#pragma unroll
    for (int kc = 0; kc < 16; ++kc)
        s += *(const float4v*)(part + (size_t)kc * NN * DO + i);
    *(float4v*)(out + i) = s;
}

extern "C" void kernel_launch(void* const* d_in, const int* in_sizes, int n_in,
                              void* d_out, int out_size, void* d_ws, size_t ws_size,
                              hipStream_t stream) {
    const float* x   = (const float*)d_in[0];
    const float* src = (const float*)d_in[1];
    const float* tgt = (const float*)d_in[2];
    const float* fw  = (const float*)d_in[3];
    const float* fb  = (const float*)d_in[4];
    float* out = (float*)d_out;

    char* ws = (char*)d_ws;
    u16*   ATB  = (u16*)ws;                                  //  2 MB: [256][4096] bf16
    u16*   YT   = (u16*)(ws + (size_t)2 * 1024 * 1024);      //  8 MB: [128][32768] bf16
    float* PART = (float*)(ws + (size_t)16 * 1024 * 1024);   // 32 MB: [16][4096][128] f32

    k1_ab  <<<64,   256, 0, stream>>>(x, fw, ATB);
    k2_y   <<<512,  256, 0, stream>>>(src, tgt, ATB, fb, YT);
    k3_part<<<1024, 256, 0, stream>>>(tgt, YT, PART);
    k4_red <<<512,  256, 0, stream>>>(PART, out);
}

// Round 8
// 374.136 us; speedup vs baseline: 1.1869x; 1.0005x over previous
//
#include <hip/hip_runtime.h>

typedef __attribute__((ext_vector_type(8))) short short8v;
typedef __attribute__((ext_vector_type(4))) float float4v;
typedef __attribute__((ext_vector_type(2))) unsigned int u32x2;
typedef __attribute__((ext_vector_type(4))) unsigned int u32x4;
typedef unsigned short u16;
typedef unsigned int u32;
typedef const __attribute__((address_space(1))) void* gas1;
typedef __attribute__((address_space(3))) void* las3;

#define NN 4096
#define EE 32768
#define DI 128
#define DO 128

__device__ __forceinline__ u16 f2bf(float f) {
    u32 u = __builtin_bit_cast(u32, f);
    u32 r = u + 0x7fffu + ((u >> 16) & 1u);   // round-to-nearest-even
    return (u16)(r >> 16);
}
__device__ __forceinline__ u32 pack2bf(float lo, float hi) {
    return (u32)f2bf(lo) | ((u32)f2bf(hi) << 16);
}
__device__ __forceinline__ void gload16(const void* g, void* l) {
    __builtin_amdgcn_global_load_lds((gas1)g, (las3)l, 16, 0, 0);
}
__device__ __forceinline__ u32 cvtpk(float lo, float hi) {
    u32 r;
    asm("v_cvt_pk_bf16_f32 %0, %1, %2" : "=v"(r) : "v"(lo), "v"(hi));
    return r;
}

// ---- helpers used by k1 only ----
template<int R, int C>
__device__ __forceinline__ void stage_f32_bf16(char* lds, const float* src, int ld) {
    constexpr int CH = C / 8;
    constexpr int ITER = (R * CH) / 256;
#pragma unroll
    for (int it = 0; it < ITER; ++it) {
        int c = it * 256 + (int)threadIdx.x;
        int row = c / CH, col8 = c % CH;
        const float* p = src + (size_t)row * ld + col8 * 8;
        float4v v0 = *(const float4v*)p;
        float4v v1 = *(const float4v*)(p + 4);
        u32x4 w;
        w[0] = pack2bf(v0[0], v0[1]);
        w[1] = pack2bf(v0[2], v0[3]);
        w[2] = pack2bf(v1[0], v1[1]);
        w[3] = pack2bf(v1[2], v1[3]);
        int kb = col8 * 16;
        *(u32x4*)(lds + row * (C * 2) + (kb ^ ((row & 7) << 4))) = w;
    }
}
template<int ROWB>
__device__ __forceinline__ short8v ldfrag(const char* base, int row16, int kk) {
    int l = (int)threadIdx.x & 63;
    int row = row16 + (l & 15);
    int kb = kk * 64 + ((l >> 4) << 4);
    return *(const short8v*)(base + row * ROWB + (kb ^ ((row & 7) << 4)));
}

// ---------- kernel 1: ATB[mo][n] = sum_i f_w[o][m*128+i] * x[n][i]  (mo = m*128+o) ----------
__global__ __launch_bounds__(256) void k1_ab(const float* __restrict__ x,
                                             const float* __restrict__ fw,
                                             u16* __restrict__ ATB) {
    __shared__ __align__(16) char lds[64 * 1024];
    char* aL = lds;              // [128 mo][128 i], ROWB 256
    char* bL = lds + 32 * 1024;  // [128 n][128 i]
    int mb = (int)blockIdx.x >> 5, nb = (int)blockIdx.x & 31;
    stage_f32_bf16<128, 128>(aL, fw + mb * 128, 2 * DI);
    stage_f32_bf16<128, 128>(bL, x + (size_t)nb * 128 * DI, DI);
    __syncthreads();
    int w = (int)threadIdx.x >> 6, l = (int)threadIdx.x & 63;
    int wr = w >> 1, wc = w & 1;
    float4v acc[4][4] = {};
#pragma unroll
    for (int kk = 0; kk < 4; ++kk) {
        short8v af[4], bf[4];
#pragma unroll
        for (int m = 0; m < 4; ++m) af[m] = ldfrag<256>(aL, wr * 64 + m * 16, kk);
#pragma unroll
        for (int n2 = 0; n2 < 4; ++n2) bf[n2] = ldfrag<256>(bL, wc * 64 + n2 * 16, kk);
#pragma unroll
        for (int m = 0; m < 4; ++m)
#pragma unroll
            for (int n2 = 0; n2 < 4; ++n2)
                acc[m][n2] = __builtin_amdgcn_mfma_f32_16x16x32_bf16(af[m], bf[n2], acc[m][n2], 0, 0, 0);
    }
#pragma unroll
    for (int m = 0; m < 4; ++m)
#pragma unroll
        for (int n2 = 0; n2 < 4; ++n2)
#pragma unroll
            for (int r = 0; r < 4; ++r) {
                int mo = mb * 128 + wr * 64 + m * 16 + ((l >> 4) << 2) + r;
                int n  = nb * 128 + wc * 64 + n2 * 16 + (l & 15);
                ATB[(size_t)mo * NN + n] = f2bf(acc[m][n2][r]);
            }
}

// ---------- kernel 2: YT[o][e] = relu(sum_mat sum_n ATB[mat][o][n]*M[n][e] + fb[o]) ----------
// grid 512 e-tiles of 64. 128 K-steps (64 src + 64 tgt), acc carried across phases.
// 2-DEEP reg prefetch, (256,2) so the ~180-VGPR live set fits with zero spills.
__global__ __launch_bounds__(256, 2) void k2_y(const float* __restrict__ src,
                                               const float* __restrict__ tgt,
                                               const u16* __restrict__ ATB,
                                               const float* __restrict__ fb,
                                               u16* __restrict__ YT) {
    __shared__ __align__(16) char lds[48 * 1024]; // ATB bufs @0,16K; Mt bufs @32K,40K
    const int eb = (int)blockIdx.x * 64;
    const int t = (int)threadIdx.x, w = t >> 6, l = t & 63;
    const int eq = t & 15, nq = t >> 4;           // 16 e-quads x 16 n-quads

    auto loadT = [&](int ks, float4v& r0, float4v& r1, float4v& r2, float4v& r3) {
        const float* M = (ks >= 64 ? tgt : src);
        const int n0 = (ks & 63) * 64;
        const float* p = M + (size_t)(n0 + nq * 4) * EE + eb + eq * 4;
        r0 = *(const float4v*)p;
        r1 = *(const float4v*)(p + EE);
        r2 = *(const float4v*)(p + 2 * EE);
        r3 = *(const float4v*)(p + 3 * EE);
    };
    auto gloadA = [&](int ks, int p) {            // ATB tile [128 o][64 n] bf16, pre-swz src
        const int mat = ks >> 6, n0 = (ks & 63) * 64;
        const u16* AB = ATB + (size_t)mat * 128 * NN + n0;
#pragma unroll
        for (int q = 0; q < 4; ++q) {
            const int s = w * 4 + q;
            const int r = s * 8 + (l >> 3);
            const u16* ga = AB + (size_t)r * NN + (((l & 7) ^ (r & 7)) << 3);
            gload16(ga, lds + p * 16384 + s * 1024);
        }
    };
    auto writeT = [&](int p, float4v& r0, float4v& r1, float4v& r2, float4v& r3) {
        char* buf = lds + 32768 + p * 8192;       // Mt [64 e][64 n] bf16, XOR-swz
#pragma unroll
        for (int j = 0; j < 4; ++j) {
            int e = eq * 4 + j;
            u32x2 w2;
            w2[0] = cvtpk(r0[j], r1[j]);
            w2[1] = cvtpk(r2[j], r3[j]);
            *(u32x2*)(buf + e * 128 + ((nq * 8) ^ ((e & 7) << 4))) = w2;
        }
    };

    float4v acc[2][4] = {};
    // step: tile ks from LDS; issue loadT(ks+2)->cur regs; writeT(next regs = tile ks+1)
    auto step = [&](int ks, float4v& c0, float4v& c1, float4v& c2, float4v& c3,
                    float4v& x0, float4v& x1, float4v& x2, float4v& x3) {
        const int nx2 = ks + 2 < 128 ? ks + 2 : 127;
        const int nx1 = ks + 1 < 128 ? ks + 1 : 127;
        loadT(nx2, c0, c1, c2, c3);                // 4 reg loads (full-step slack)
        gloadA(nx1, (ks + 1) & 1);                 // 4 gload_lds  (full-step slack)
        asm volatile("s_waitcnt vmcnt(8)" ::: "memory");  // loadT(ks+1)+gloadA(ks) landed
        __builtin_amdgcn_sched_barrier(0);
        const char* bufA = lds + (ks & 1) * 16384;
        const char* bufB = lds + 32768 + (ks & 1) * 8192;
        short8v af[2][2], bfr[2][4];
#pragma unroll
        for (int kk = 0; kk < 2; ++kk) {
#pragma unroll
            for (int m = 0; m < 2; ++m)
                af[kk][m] = ldfrag<128>(bufA, w * 32 + m * 16, kk);
#pragma unroll
            for (int n2 = 0; n2 < 4; ++n2)
                bfr[kk][n2] = ldfrag<128>(bufB, n2 * 16, kk);
        }
#pragma unroll
        for (int kk = 0; kk < 2; ++kk)
#pragma unroll
            for (int m = 0; m < 2; ++m)
#pragma unroll
                for (int n2 = 0; n2 < 4; ++n2)
                    acc[m][n2] = __builtin_amdgcn_mfma_f32_16x16x32_bf16(
                        af[kk][m], bfr[kk][n2], acc[m][n2], 0, 0, 0);
        writeT((ks + 1) & 1, x0, x1, x2, x3);      // tile ks+1 -> Mt buf, regs already ready
        asm volatile("s_waitcnt lgkmcnt(0)" ::: "memory");
        __builtin_amdgcn_sched_barrier(0);
        __builtin_amdgcn_s_barrier();
    };

    float4v a0, a1, a2, a3, b0, b1, b2, b3;       // two named reg sets (static indexing)
    loadT(0, a0, a1, a2, a3);
    asm volatile("s_waitcnt vmcnt(0)" ::: "memory");   // prologue-only drain
    writeT(0, a0, a1, a2, a3);
    loadT(1, b0, b1, b2, b3);
    gloadA(0, 0);
    __syncthreads();                               // prologue-only full drain

    for (int ks = 0; ks < 128; ks += 2) {
        step(ks,     a0, a1, a2, a3,  b0, b1, b2, b3);  // refill a<-tile ks+2, write b=tile ks+1
        step(ks + 1, b0, b1, b2, b3,  a0, a1, a2, a3);  // refill b<-tile ks+3, write a=tile ks+2
    }
#pragma unroll
    for (int m = 0; m < 2; ++m)
#pragma unroll
        for (int n2 = 0; n2 < 4; ++n2)
#pragma unroll
            for (int r = 0; r < 4; ++r) {
                const int o = w * 32 + m * 16 + ((l >> 4) << 2) + r;
                const int e = eb + n2 * 16 + (l & 15);
                float v = acc[m][n2][r] + fb[o];
                v = v > 0.f ? v : 0.f;
                YT[(size_t)o * EE + e] = f2bf(v);
            }
}

// ---------- kernel 3: part[kc][n][o] = sum_{e in chunk kc} tgt[n][e] * YT[o][e] ----------
// grid 1024 = 64 mb x 16 kc. LDS 48KB -> 3 blocks/CU. (unchanged — near floor)
__global__ __launch_bounds__(256, 3) void k3_part(const float* __restrict__ tgt,
                                                  const u16* __restrict__ YT,
                                                  float* __restrict__ part) {
    __shared__ __align__(16) char lds[48 * 1024]; // T bufs @0,8K (bf16); Y bufs @16K,32K
    const int bid = (int)blockIdx.x;
    const int mb = bid & 63, kc = bid >> 6;
    const int e0 = kc * 2048;
    const int t = (int)threadIdx.x, w = t >> 6, l = t & 63;
    const int wr = w >> 1, wc = w & 1;
    const int trow = t >> 2, te0 = (t & 3) * 16;  // 64 rows x 4 col-chunks of 16 e

    float4v v0, v1, v2, v3;
    auto loadT = [&](int es) {                    // tgt[mb*64+trow][ec+te0..+15] -> regs
        const float* p = tgt + (size_t)(mb * 64 + trow) * EE + e0 + es * 64 + te0;
        v0 = *(const float4v*)p;
        v1 = *(const float4v*)(p + 4);
        v2 = *(const float4v*)(p + 8);
        v3 = *(const float4v*)(p + 12);
    };
    auto gloadY = [&](int es, int p) {            // Y tile [128 o][64 e] bf16, pre-swz src
        const int ec = e0 + es * 64;
#pragma unroll
        for (int q = 0; q < 4; ++q) {
            const int s = w * 4 + q;
            const int r = s * 8 + (l >> 3);
            const u16* gy = YT + (size_t)r * EE + ec + (((l & 7) ^ (r & 7)) << 3);
            gload16(gy, lds + 16384 + p * 16384 + s * 1024);
        }
    };
    auto writeT = [&](int p) {                    // regs -> T [64 n][64 e] bf16, XOR-swz
        char* buf = lds + p * 8192;
        u32x4 wA, wB;
        wA[0] = cvtpk(v0[0], v0[1]); wA[1] = cvtpk(v0[2], v0[3]);
        wA[2] = cvtpk(v1[0], v1[1]); wA[3] = cvtpk(v1[2], v1[3]);
        wB[0] = cvtpk(v2[0], v2[1]); wB[1] = cvtpk(v2[2], v2[3]);
        wB[2] = cvtpk(v3[0], v3[1]); wB[3] = cvtpk(v3[2], v3[3]);
        *(u32x4*)(buf + trow * 128 + ((te0 * 2) ^ ((trow & 7) << 4))) = wA;
        *(u32x4*)(buf + trow * 128 + ((te0 * 2 + 16) ^ ((trow & 7) << 4))) = wB;
    };

    loadT(0);
    gloadY(0, 0);
    writeT(0);
    __syncthreads();   // prologue only

    float4v acc[2][4] = {};
    for (int es = 0; es < 32; ++es) {
        const int nx = es < 31 ? es + 1 : 31;
        loadT(nx);                                 // 4 reg loads (FIRST)
        gloadY(nx, (es + 1) & 1);                  // 4 gload_lds
        asm volatile("s_waitcnt vmcnt(8)" ::: "memory");   // Y(es) landed (own wave)
        __builtin_amdgcn_sched_barrier(0);
        __builtin_amdgcn_s_barrier();              // all waves' Y(es) landed (cross-wave reads)
        const char* bufT = lds + (es & 1) * 8192;
        const char* bufY = lds + 16384 + (es & 1) * 16384;
        short8v af[2][2], bfr[2][4];
#pragma unroll
        for (int kk = 0; kk < 2; ++kk) {
#pragma unroll
            for (int m = 0; m < 2; ++m)
                af[kk][m] = ldfrag<128>(bufT, wr * 32 + m * 16, kk);
#pragma unroll
            for (int n2 = 0; n2 < 4; ++n2)
                bfr[kk][n2] = ldfrag<128>(bufY, wc * 64 + n2 * 16, kk);
        }
#pragma unroll
        for (int kk = 0; kk < 2; ++kk)
#pragma unroll
            for (int m = 0; m < 2; ++m)
#pragma unroll
                for (int n2 = 0; n2 < 4; ++n2)
                    acc[m][n2] = __builtin_amdgcn_mfma_f32_16x16x32_bf16(
                        af[kk][m], bfr[kk][n2], acc[m][n2], 0, 0, 0);
        asm volatile("s_waitcnt vmcnt(4)" ::: "memory");   // loadT(es+1) regs ready
        __builtin_amdgcn_sched_barrier(0);
        writeT((es + 1) & 1);
        asm volatile("s_waitcnt lgkmcnt(0)" ::: "memory");
        __builtin_amdgcn_sched_barrier(0);
        __builtin_amdgcn_s_barrier();              // T(es+1) published
    }
#pragma unroll
    for (int m = 0; m < 2; ++m)
#pragma unroll
        for (int n2 = 0; n2 < 4; ++n2)
#pragma unroll
            for (int r = 0; r < 4; ++r) {
                const int n = mb * 64 + wr * 32 + m * 16 + ((l >> 4) << 2) + r;
                const int o = wc * 64 + n2 * 16 + (l & 15);
                part[((size_t)kc * NN + n) * DO + o] = acc[m][n2][r];
            }
}

// ---------- kernel 4: out = sum_kc part[kc] ----------
__global__ __launch_bounds__(256) void k4_red(const float* __restrict__ part,
                                              float* __restrict__ out) {
    size_t i = ((size_t)blockIdx.x * 256 + threadIdx.x) * 4;
    float4v s = {0.f, 0.f, 0.f, 0.f};
#pragma unroll
    for (int kc = 0; kc < 16; ++kc)
        s += *(const float4v*)(part + (size_t)kc * NN * DO + i);
    *(float4v*)(out + i) = s;
}

extern "C" void kernel_launch(void* const* d_in, const int* in_sizes, int n_in,
                              void* d_out, int out_size, void* d_ws, size_t ws_size,
                              hipStream_t stream) {
    const float* x   = (const float*)d_in[0];
    const float* src = (const float*)d_in[1];
    const float* tgt = (const float*)d_in[2];
    const float* fw  = (const float*)d_in[3];
    const float* fb  = (const float*)d_in[4];
    float* out = (float*)d_out;

    char* ws = (char*)d_ws;
    u16*   ATB  = (u16*)ws;                                  //  2 MB: [256][4096] bf16
    u16*   YT   = (u16*)(ws + (size_t)2 * 1024 * 1024);      //  8 MB: [128][32768] bf16
    float* PART = (float*)(ws + (size_t)16 * 1024 * 1024);   // 32 MB: [16][4096][128] f32

    k1_ab  <<<64,   256, 0, stream>>>(x, fw, ATB);
    k2_y   <<<512,  256, 0, stream>>>(src, tgt, ATB, fb, YT);
    k3_part<<<1024, 256, 0, stream>>>(tgt, YT, PART);
    k4_red <<<512,  256, 0, stream>>>(PART, out);
}

// Round 9
// 366.969 us; speedup vs baseline: 1.2101x; 1.0195x over previous
//
#include <hip/hip_runtime.h>

typedef __attribute__((ext_vector_type(8))) short short8v;
typedef __attribute__((ext_vector_type(4))) float float4v;
typedef __attribute__((ext_vector_type(2))) unsigned int u32x2;
typedef __attribute__((ext_vector_type(4))) unsigned int u32x4;
typedef unsigned short u16;
typedef unsigned int u32;
typedef const __attribute__((address_space(1))) void* gas1;
typedef __attribute__((address_space(3))) void* las3;

#define NN 4096
#define EE 32768
#define DI 128
#define DO 128

__device__ __forceinline__ u16 f2bf(float f) {
    u32 u = __builtin_bit_cast(u32, f);
    u32 r = u + 0x7fffu + ((u >> 16) & 1u);   // round-to-nearest-even
    return (u16)(r >> 16);
}
__device__ __forceinline__ u32 pack2bf(float lo, float hi) {
    return (u32)f2bf(lo) | ((u32)f2bf(hi) << 16);
}
__device__ __forceinline__ void gload16(const void* g, void* l) {
    __builtin_amdgcn_global_load_lds((gas1)g, (las3)l, 16, 0, 0);
}
__device__ __forceinline__ u32 cvtpk(float lo, float hi) {
    u32 r;
    asm("v_cvt_pk_bf16_f32 %0, %1, %2" : "=v"(r) : "v"(lo), "v"(hi));
    return r;
}

// ---- helpers used by k1 only ----
template<int R, int C>
__device__ __forceinline__ void stage_f32_bf16(char* lds, const float* src, int ld) {
    constexpr int CH = C / 8;
    constexpr int ITER = (R * CH) / 256;
#pragma unroll
    for (int it = 0; it < ITER; ++it) {
        int c = it * 256 + (int)threadIdx.x;
        int row = c / CH, col8 = c % CH;
        const float* p = src + (size_t)row * ld + col8 * 8;
        float4v v0 = *(const float4v*)p;
        float4v v1 = *(const float4v*)(p + 4);
        u32x4 w;
        w[0] = pack2bf(v0[0], v0[1]);
        w[1] = pack2bf(v0[2], v0[3]);
        w[2] = pack2bf(v1[0], v1[1]);
        w[3] = pack2bf(v1[2], v1[3]);
        int kb = col8 * 16;
        *(u32x4*)(lds + row * (C * 2) + (kb ^ ((row & 7) << 4))) = w;
    }
}
template<int ROWB>
__device__ __forceinline__ short8v ldfrag(const char* base, int row16, int kk) {
    int l = (int)threadIdx.x & 63;
    int row = row16 + (l & 15);
    int kb = kk * 64 + ((l >> 4) << 4);
    return *(const short8v*)(base + row * ROWB + (kb ^ ((row & 7) << 4)));
}

// ---------- kernel 1: ATB[mo][n] = sum_i f_w[o][m*128+i] * x[n][i]  (mo = m*128+o) ----------
__global__ __launch_bounds__(256) void k1_ab(const float* __restrict__ x,
                                             const float* __restrict__ fw,
                                             u16* __restrict__ ATB) {
    __shared__ __align__(16) char lds[64 * 1024];
    char* aL = lds;              // [128 mo][128 i], ROWB 256
    char* bL = lds + 32 * 1024;  // [128 n][128 i]
    int mb = (int)blockIdx.x >> 5, nb = (int)blockIdx.x & 31;
    stage_f32_bf16<128, 128>(aL, fw + mb * 128, 2 * DI);
    stage_f32_bf16<128, 128>(bL, x + (size_t)nb * 128 * DI, DI);
    __syncthreads();
    int w = (int)threadIdx.x >> 6, l = (int)threadIdx.x & 63;
    int wr = w >> 1, wc = w & 1;
    float4v acc[4][4] = {};
#pragma unroll
    for (int kk = 0; kk < 4; ++kk) {
        short8v af[4], bf[4];
#pragma unroll
        for (int m = 0; m < 4; ++m) af[m] = ldfrag<256>(aL, wr * 64 + m * 16, kk);
#pragma unroll
        for (int n2 = 0; n2 < 4; ++n2) bf[n2] = ldfrag<256>(bL, wc * 64 + n2 * 16, kk);
#pragma unroll
        for (int m = 0; m < 4; ++m)
#pragma unroll
            for (int n2 = 0; n2 < 4; ++n2)
                acc[m][n2] = __builtin_amdgcn_mfma_f32_16x16x32_bf16(af[m], bf[n2], acc[m][n2], 0, 0, 0);
    }
#pragma unroll
    for (int m = 0; m < 4; ++m)
#pragma unroll
        for (int n2 = 0; n2 < 4; ++n2)
#pragma unroll
            for (int r = 0; r < 4; ++r) {
                int mo = mb * 128 + wr * 64 + m * 16 + ((l >> 4) << 2) + r;
                int n  = nb * 128 + wc * 64 + n2 * 16 + (l & 15);
                ATB[(size_t)mo * NN + n] = f2bf(acc[m][n2][r]);
            }
}

// ---------- kernel 2: YT[o][e] = relu(sum_mat sum_n ATB[mat][o][n]*M[n][e] + fb[o]) ----------
// grid 512 e-tiles of 64. 128 K-steps (64 src + 64 tgt), acc carried.
// A-frags: DIRECT global->reg (L2-resident ATB, fragment layout == row-major), 1 step ahead.
// M: global->reg (2-deep) ->cvtpk-> transposed bf16 LDS dbuf. LDS 16KB -> 3 blocks/CU.
// No manual vmcnt: compiler emits counted waits for register loads. One barrier/step.
__global__ __launch_bounds__(256, 3) void k2_y(const float* __restrict__ src,
                                               const float* __restrict__ tgt,
                                               const u16* __restrict__ ATB,
                                               const float* __restrict__ fb,
                                               u16* __restrict__ YT) {
    __shared__ __align__(16) char lds[16 * 1024]; // Mt bufs @0,8K: [64 e][64 n] bf16, XOR-swz
    const int eb = (int)blockIdx.x * 64;
    const int t = (int)threadIdx.x, w = t >> 6, l = t & 63;
    const int eq = t & 15, nq = t >> 4;           // 16 e-quads x 16 n-quads

    auto loadM = [&](int ks, float4v& r0, float4v& r1, float4v& r2, float4v& r3) {
        const float* M = (ks >= 64 ? tgt : src);
        const int n0 = (ks & 63) * 64;
        const float* p = M + (size_t)(n0 + nq * 4) * EE + eb + eq * 4;
        r0 = *(const float4v*)p;
        r1 = *(const float4v*)(p + EE);
        r2 = *(const float4v*)(p + 2 * EE);
        r3 = *(const float4v*)(p + 3 * EE);
    };
    // A-frag direct loads: row o = w*32 + m*16 + (l&15); 8 shorts at n0 + kk*32 + (l>>4)*8
    auto loadA = [&](int ks, short8v& A00, short8v& A01, short8v& A10, short8v& A11) {
        const int mat = ks >> 6, n0 = (ks & 63) * 64;
        const u16* base = ATB + (size_t)(mat * 128 + w * 32 + (l & 15)) * NN
                          + n0 + ((l >> 4) << 3);
        A00 = *(const short8v*)(base);                       // m=0, kk=0
        A01 = *(const short8v*)(base + 32);                  // m=0, kk=1
        A10 = *(const short8v*)(base + (size_t)16 * NN);     // m=1, kk=0
        A11 = *(const short8v*)(base + (size_t)16 * NN + 32);// m=1, kk=1
    };
    auto writeT = [&](int p, float4v& r0, float4v& r1, float4v& r2, float4v& r3) {
        char* buf = lds + p * 8192;
#pragma unroll
        for (int j = 0; j < 4; ++j) {
            int e = eq * 4 + j;
            u32x2 w2;
            w2[0] = cvtpk(r0[j], r1[j]);
            w2[1] = cvtpk(r2[j], r3[j]);
            *(u32x2*)(buf + e * 128 + ((nq * 8) ^ ((e & 7) << 4))) = w2;
        }
    };

    float4v acc[2][4] = {};
    // step ks: MFMA uses Acur (=A(ks), loaded last step) + Mt buf[ks&1];
    //          issues loadM(ks+2)->Mcur, loadA(ks+1)->Anext; writes Mnext(=M(ks+1)) to buf.
    auto step = [&](int ks,
                    short8v& c00, short8v& c01, short8v& c10, short8v& c11,
                    short8v& x00, short8v& x01, short8v& x10, short8v& x11,
                    float4v& m0, float4v& m1, float4v& m2, float4v& m3,
                    float4v& y0, float4v& y1, float4v& y2, float4v& y3) {
        const int nx2 = ks + 2 < 128 ? ks + 2 : 127;
        const int nx1 = ks + 1 < 128 ? ks + 1 : 127;
        loadM(nx2, m0, m1, m2, m3);               // 4 VMEM (full-step slack)
        loadA(nx1, x00, x01, x10, x11);           // 4 VMEM from L2 (full-step slack)
        const char* bufB = lds + (ks & 1) * 8192;
        short8v bfr[2][4];
#pragma unroll
        for (int kk = 0; kk < 2; ++kk)
#pragma unroll
            for (int n2 = 0; n2 < 4; ++n2)
                bfr[kk][n2] = ldfrag<128>(bufB, n2 * 16, kk);
        // compiler inserts counted vmcnt here for c** (loaded last step) + lgkm for bfr
#pragma unroll
        for (int n2 = 0; n2 < 4; ++n2) {
            acc[0][n2] = __builtin_amdgcn_mfma_f32_16x16x32_bf16(c00, bfr[0][n2], acc[0][n2], 0, 0, 0);
            acc[1][n2] = __builtin_amdgcn_mfma_f32_16x16x32_bf16(c10, bfr[0][n2], acc[1][n2], 0, 0, 0);
            acc[0][n2] = __builtin_amdgcn_mfma_f32_16x16x32_bf16(c01, bfr[1][n2], acc[0][n2], 0, 0, 0);
            acc[1][n2] = __builtin_amdgcn_mfma_f32_16x16x32_bf16(c11, bfr[1][n2], acc[1][n2], 0, 0, 0);
        }
        writeT((ks + 1) & 1, y0, y1, y2, y3);     // M(ks+1) regs, loaded last step
        asm volatile("s_waitcnt lgkmcnt(0)" ::: "memory");
        __builtin_amdgcn_sched_barrier(0);
        __builtin_amdgcn_s_barrier();
    };

    float4v aM0, aM1, aM2, aM3, bM0, bM1, bM2, bM3;
    short8v aA00, aA01, aA10, aA11, bA00, bA01, bA10, bA11;
    loadM(0, aM0, aM1, aM2, aM3);
    asm volatile("s_waitcnt vmcnt(0)" ::: "memory");   // prologue-only drain
    writeT(0, aM0, aM1, aM2, aM3);                     // Mt(0) -> buf0
    loadA(0, aA00, aA01, aA10, aA11);                  // A(0) for step 0
    loadM(1, bM0, bM1, bM2, bM3);                      // M(1) for end of step 0
    __syncthreads();                                    // prologue-only full drain

    for (int ks = 0; ks < 128; ks += 2) {
        step(ks,     aA00, aA01, aA10, aA11,  bA00, bA01, bA10, bA11,
                     aM0, aM1, aM2, aM3,      bM0, bM1, bM2, bM3);
        step(ks + 1, bA00, bA01, bA10, bA11,  aA00, aA01, aA10, aA11,
                     bM0, bM1, bM2, bM3,      aM0, aM1, aM2, aM3);
    }
#pragma unroll
    for (int m = 0; m < 2; ++m)
#pragma unroll
        for (int n2 = 0; n2 < 4; ++n2)
#pragma unroll
            for (int r = 0; r < 4; ++r) {
                const int o = w * 32 + m * 16 + ((l >> 4) << 2) + r;
                const int e = eb + n2 * 16 + (l & 15);
                float v = acc[m][n2][r] + fb[o];
                v = v > 0.f ? v : 0.f;
                YT[(size_t)o * EE + e] = f2bf(v);
            }
}

// ---------- kernel 3: part[kc][n][o] = sum_{e in chunk kc} tgt[n][e] * YT[o][e] ----------
// grid 1024 = 64 mb x 16 kc. LDS 48KB -> 3 blocks/CU. (unchanged — near floor)
__global__ __launch_bounds__(256, 3) void k3_part(const float* __restrict__ tgt,
                                                  const u16* __restrict__ YT,
                                                  float* __restrict__ part) {
    __shared__ __align__(16) char lds[48 * 1024]; // T bufs @0,8K (bf16); Y bufs @16K,32K
    const int bid = (int)blockIdx.x;
    const int mb = bid & 63, kc = bid >> 6;
    const int e0 = kc * 2048;
    const int t = (int)threadIdx.x, w = t >> 6, l = t & 63;
    const int wr = w >> 1, wc = w & 1;
    const int trow = t >> 2, te0 = (t & 3) * 16;  // 64 rows x 4 col-chunks of 16 e

    float4v v0, v1, v2, v3;
    auto loadT = [&](int es) {                    // tgt[mb*64+trow][ec+te0..+15] -> regs
        const float* p = tgt + (size_t)(mb * 64 + trow) * EE + e0 + es * 64 + te0;
        v0 = *(const float4v*)p;
        v1 = *(const float4v*)(p + 4);
        v2 = *(const float4v*)(p + 8);
        v3 = *(const float4v*)(p + 12);
    };
    auto gloadY = [&](int es, int p) {            // Y tile [128 o][64 e] bf16, pre-swz src
        const int ec = e0 + es * 64;
#pragma unroll
        for (int q = 0; q < 4; ++q) {
            const int s = w * 4 + q;
            const int r = s * 8 + (l >> 3);
            const u16* gy = YT + (size_t)r * EE + ec + (((l & 7) ^ (r & 7)) << 3);
            gload16(gy, lds + 16384 + p * 16384 + s * 1024);
        }
    };
    auto writeT = [&](int p) {                    // regs -> T [64 n][64 e] bf16, XOR-swz
        char* buf = lds + p * 8192;
        u32x4 wA, wB;
        wA[0] = cvtpk(v0[0], v0[1]); wA[1] = cvtpk(v0[2], v0[3]);
        wA[2] = cvtpk(v1[0], v1[1]); wA[3] = cvtpk(v1[2], v1[3]);
        wB[0] = cvtpk(v2[0], v2[1]); wB[1] = cvtpk(v2[2], v2[3]);
        wB[2] = cvtpk(v3[0], v3[1]); wB[3] = cvtpk(v3[2], v3[3]);
        *(u32x4*)(buf + trow * 128 + ((te0 * 2) ^ ((trow & 7) << 4))) = wA;
        *(u32x4*)(buf + trow * 128 + ((te0 * 2 + 16) ^ ((trow & 7) << 4))) = wB;
    };

    loadT(0);
    gloadY(0, 0);
    writeT(0);
    __syncthreads();   // prologue only

    float4v acc[2][4] = {};
    for (int es = 0; es < 32; ++es) {
        const int nx = es < 31 ? es + 1 : 31;
        loadT(nx);                                 // 4 reg loads (FIRST)
        gloadY(nx, (es + 1) & 1);                  // 4 gload_lds
        asm volatile("s_waitcnt vmcnt(8)" ::: "memory");   // Y(es) landed (own wave)
        __builtin_amdgcn_sched_barrier(0);
        __builtin_amdgcn_s_barrier();              // all waves' Y(es) landed (cross-wave reads)
        const char* bufT = lds + (es & 1) * 8192;
        const char* bufY = lds + 16384 + (es & 1) * 16384;
        short8v af[2][2], bfr[2][4];
#pragma unroll
        for (int kk = 0; kk < 2; ++kk) {
#pragma unroll
            for (int m = 0; m < 2; ++m)
                af[kk][m] = ldfrag<128>(bufT, wr * 32 + m * 16, kk);
#pragma unroll
            for (int n2 = 0; n2 < 4; ++n2)
                bfr[kk][n2] = ldfrag<128>(bufY, wc * 64 + n2 * 16, kk);
        }
#pragma unroll
        for (int kk = 0; kk < 2; ++kk)
#pragma unroll
            for (int m = 0; m < 2; ++m)
#pragma unroll
                for (int n2 = 0; n2 < 4; ++n2)
                    acc[m][n2] = __builtin_amdgcn_mfma_f32_16x16x32_bf16(
                        af[kk][m], bfr[kk][n2], acc[m][n2], 0, 0, 0);
        asm volatile("s_waitcnt vmcnt(4)" ::: "memory");   // loadT(es+1) regs ready
        __builtin_amdgcn_sched_barrier(0);
        writeT((es + 1) & 1);
        asm volatile("s_waitcnt lgkmcnt(0)" ::: "memory");
        __builtin_amdgcn_sched_barrier(0);
        __builtin_amdgcn_s_barrier();              // T(es+1) published
    }
#pragma unroll
    for (int m = 0; m < 2; ++m)
#pragma unroll
        for (int n2 = 0; n2 < 4; ++n2)
#pragma unroll
            for (int r = 0; r < 4; ++r) {
                const int n = mb * 64 + wr * 32 + m * 16 + ((l >> 4) << 2) + r;
                const int o = wc * 64 + n2 * 16 + (l & 15);
                part[((size_t)kc * NN + n) * DO + o] = acc[m][n2][r];
            }
}

// ---------- kernel 4: out = sum_kc part[kc] ----------
__global__ __launch_bounds__(256) void k4_red(const float* __restrict__ part,
                                              float* __restrict__ out) {
    size_t i = ((size_t)blockIdx.x * 256 + threadIdx.x) * 4;
    float4v s = {0.f, 0.f, 0.f, 0.f};
#pragma unroll
    for (int kc = 0; kc < 16; ++kc)
        s += *(const float4v*)(part + (size_t)kc * NN * DO + i);
    *(float4v*)(out + i) = s;
}

extern "C" void kernel_launch(void* const* d_in, const int* in_sizes, int n_in,
                              void* d_out, int out_size, void* d_ws, size_t ws_size,
                              hipStream_t stream) {
    const float* x   = (const float*)d_in[0];
    const float* src = (const float*)d_in[1];
    const float* tgt = (const float*)d_in[2];
    const float* fw  = (const float*)d_in[3];
    const float* fb  = (const float*)d_in[4];
    float* out = (float*)d_out;

    char* ws = (char*)d_ws;
    u16*   ATB  = (u16*)ws;                                  //  2 MB: [256][4096] bf16
    u16*   YT   = (u16*)(ws + (size_t)2 * 1024 * 1024);      //  8 MB: [128][32768] bf16
    float* PART = (float*)(ws + (size_t)16 * 1024 * 1024);   // 32 MB: [16][4096][128] f32

    k1_ab  <<<64,   256, 0, stream>>>(x, fw, ATB);
    k2_y   <<<512,  256, 0, stream>>>(src, tgt, ATB, fb, YT);
    k3_part<<<1024, 256, 0, stream>>>(tgt, YT, PART);
    k4_red <<<512,  256, 0, stream>>>(PART, out);
}

// Round 10
// 339.522 us; speedup vs baseline: 1.3079x; 1.0808x over previous
//
#include <hip/hip_runtime.h>

typedef __attribute__((ext_vector_type(8))) short short8v;
typedef __attribute__((ext_vector_type(4))) float float4v;
typedef __attribute__((ext_vector_type(2))) unsigned int u32x2;
typedef __attribute__((ext_vector_type(4))) unsigned int u32x4;
typedef unsigned short u16;
typedef unsigned int u32;
typedef const __attribute__((address_space(1))) void* gas1;
typedef __attribute__((address_space(3))) void* las3;

#define NN 4096
#define EE 32768
#define DI 128
#define DO 128

__device__ __forceinline__ u16 f2bf(float f) {
    u32 u = __builtin_bit_cast(u32, f);
    u32 r = u + 0x7fffu + ((u >> 16) & 1u);   // round-to-nearest-even
    return (u16)(r >> 16);
}
__device__ __forceinline__ u32 pack2bf(float lo, float hi) {
    return (u32)f2bf(lo) | ((u32)f2bf(hi) << 16);
}
__device__ __forceinline__ void gload16(const void* g, void* l) {
    __builtin_amdgcn_global_load_lds((gas1)g, (las3)l, 16, 0, 0);
}
__device__ __forceinline__ u32 cvtpk(float lo, float hi) {
    u32 r;
    asm("v_cvt_pk_bf16_f32 %0, %1, %2" : "=v"(r) : "v"(lo), "v"(hi));
    return r;
}

// ---- helpers used by k1 only ----
template<int R, int C>
__device__ __forceinline__ void stage_f32_bf16(char* lds, const float* src, int ld) {
    constexpr int CH = C / 8;
    constexpr int ITER = (R * CH) / 256;
#pragma unroll
    for (int it = 0; it < ITER; ++it) {
        int c = it * 256 + (int)threadIdx.x;
        int row = c / CH, col8 = c % CH;
        const float* p = src + (size_t)row * ld + col8 * 8;
        float4v v0 = *(const float4v*)p;
        float4v v1 = *(const float4v*)(p + 4);
        u32x4 w;
        w[0] = pack2bf(v0[0], v0[1]);
        w[1] = pack2bf(v0[2], v0[3]);
        w[2] = pack2bf(v1[0], v1[1]);
        w[3] = pack2bf(v1[2], v1[3]);
        int kb = col8 * 16;
        *(u32x4*)(lds + row * (C * 2) + (kb ^ ((row & 7) << 4))) = w;
    }
}
template<int ROWB>
__device__ __forceinline__ short8v ldfrag(const char* base, int row16, int kk) {
    int l = (int)threadIdx.x & 63;
    int row = row16 + (l & 15);
    int kb = kk * 64 + ((l >> 4) << 4);
    return *(const short8v*)(base + row * ROWB + (kb ^ ((row & 7) << 4)));
}

// ---------- kernel 1: ATB[mo][n] = sum_i f_w[o][m*128+i] * x[n][i]  (mo = m*128+o) ----------
__global__ __launch_bounds__(256) void k1_ab(const float* __restrict__ x,
                                             const float* __restrict__ fw,
                                             u16* __restrict__ ATB) {
    __shared__ __align__(16) char lds[64 * 1024];
    char* aL = lds;              // [128 mo][128 i], ROWB 256
    char* bL = lds + 32 * 1024;  // [128 n][128 i]
    int mb = (int)blockIdx.x >> 5, nb = (int)blockIdx.x & 31;
    stage_f32_bf16<128, 128>(aL, fw + mb * 128, 2 * DI);
    stage_f32_bf16<128, 128>(bL, x + (size_t)nb * 128 * DI, DI);
    __syncthreads();
    int w = (int)threadIdx.x >> 6, l = (int)threadIdx.x & 63;
    int wr = w >> 1, wc = w & 1;
    float4v acc[4][4] = {};
#pragma unroll
    for (int kk = 0; kk < 4; ++kk) {
        short8v af[4], bf[4];
#pragma unroll
        for (int m = 0; m < 4; ++m) af[m] = ldfrag<256>(aL, wr * 64 + m * 16, kk);
#pragma unroll
        for (int n2 = 0; n2 < 4; ++n2) bf[n2] = ldfrag<256>(bL, wc * 64 + n2 * 16, kk);
#pragma unroll
        for (int m = 0; m < 4; ++m)
#pragma unroll
            for (int n2 = 0; n2 < 4; ++n2)
                acc[m][n2] = __builtin_amdgcn_mfma_f32_16x16x32_bf16(af[m], bf[n2], acc[m][n2], 0, 0, 0);
    }
#pragma unroll
    for (int m = 0; m < 4; ++m)
#pragma unroll
        for (int n2 = 0; n2 < 4; ++n2)
#pragma unroll
            for (int r = 0; r < 4; ++r) {
                int mo = mb * 128 + wr * 64 + m * 16 + ((l >> 4) << 2) + r;
                int n  = nb * 128 + wc * 64 + n2 * 16 + (l & 15);
                ATB[(size_t)mo * NN + n] = f2bf(acc[m][n2][r]);
            }
}

// ---------- kernel 2: YT[o][e] = relu(sum_mat sum_n ATB[mat][o][n]*M[n][e] + fb[o]) ----------
// R5's proven structure, verbatim: grid 512 e-tiles of 64; 128 K-steps (64 src + 64 tgt).
// ATB: gload_lds dbuf (own-wave rows -> no barrier needed for A reads).
// M: global->reg->cvtpk->transposed bf16 LDS dbuf (1-deep).
// Counted vmcnt(8)/(4), lgkmcnt(0) + ONE raw s_barrier per step — never vmcnt(0).
__global__ __launch_bounds__(256, 2) void k2_y(const float* __restrict__ src,
                                               const float* __restrict__ tgt,
                                               const u16* __restrict__ ATB,
                                               const float* __restrict__ fb,
                                               u16* __restrict__ YT) {
    __shared__ __align__(16) char lds[48 * 1024]; // ATB bufs @0,16K; Mt bufs @32K,40K
    const int eb = (int)blockIdx.x * 64;
    const int t = (int)threadIdx.x, w = t >> 6, l = t & 63;
    const int eq = t & 15, nq = t >> 4;           // 16 e-quads x 16 n-quads

    float4v r0, r1, r2, r3;
    auto loadT = [&](int ks) {                    // M[n0+nq*4 .. +3][eb+eq*4 .. +3] -> regs
        const float* M = (ks >= 64 ? tgt : src);
        const int n0 = (ks & 63) * 64;
        const float* p = M + (size_t)(n0 + nq * 4) * EE + eb + eq * 4;
        r0 = *(const float4v*)p;
        r1 = *(const float4v*)(p + EE);
        r2 = *(const float4v*)(p + 2 * EE);
        r3 = *(const float4v*)(p + 3 * EE);
    };
    auto gloadA = [&](int ks, int p) {            // ATB tile [128 o][64 n] bf16, pre-swz src
        const int mat = ks >> 6, n0 = (ks & 63) * 64;
        const u16* AB = ATB + (size_t)mat * 128 * NN + n0;
#pragma unroll
        for (int q = 0; q < 4; ++q) {
            const int s = w * 4 + q;
            const int r = s * 8 + (l >> 3);
            const u16* ga = AB + (size_t)r * NN + (((l & 7) ^ (r & 7)) << 3);
            gload16(ga, lds + p * 16384 + s * 1024);
        }
    };
    auto writeT = [&](int p) {                    // regs -> Mt [64 e][64 n] bf16, XOR-swz
        char* buf = lds + 32768 + p * 8192;
#pragma unroll
        for (int j = 0; j < 4; ++j) {
            int e = eq * 4 + j;
            u32x2 w2;
            w2[0] = cvtpk(r0[j], r1[j]);
            w2[1] = cvtpk(r2[j], r3[j]);
            *(u32x2*)(buf + e * 128 + ((nq * 8) ^ ((e & 7) << 4))) = w2;
        }
    };

    loadT(0);
    gloadA(0, 0);
    writeT(0);
    __syncthreads();   // prologue only (drains once; Mt(0)+ATB(0) visible)

    float4v acc[2][4] = {};
    for (int ks = 0; ks < 128; ++ks) {
        const int nx = ks < 127 ? ks + 1 : 127;   // last-step dup keeps vmcnt counts exact
        loadT(nx);                                 // 4 reg loads (issued FIRST)
        gloadA(nx, (ks + 1) & 1);                  // 4 gload_lds
        asm volatile("s_waitcnt vmcnt(8)" ::: "memory");   // ATB(ks) landed; 8 in flight
        __builtin_amdgcn_sched_barrier(0);
        const char* bufA = lds + (ks & 1) * 16384;
        const char* bufB = lds + 32768 + (ks & 1) * 8192;
        short8v af[2][2], bfr[2][4];
#pragma unroll
        for (int kk = 0; kk < 2; ++kk) {
#pragma unroll
            for (int m = 0; m < 2; ++m)
                af[kk][m] = ldfrag<128>(bufA, w * 32 + m * 16, kk);
#pragma unroll
            for (int n2 = 0; n2 < 4; ++n2)
                bfr[kk][n2] = ldfrag<128>(bufB, n2 * 16, kk);
        }
#pragma unroll
        for (int kk = 0; kk < 2; ++kk)
#pragma unroll
            for (int m = 0; m < 2; ++m)
#pragma unroll
                for (int n2 = 0; n2 < 4; ++n2)
                    acc[m][n2] = __builtin_amdgcn_mfma_f32_16x16x32_bf16(
                        af[kk][m], bfr[kk][n2], acc[m][n2], 0, 0, 0);
        asm volatile("s_waitcnt vmcnt(4)" ::: "memory");   // loadT(ks+1) regs ready
        __builtin_amdgcn_sched_barrier(0);
        writeT((ks + 1) & 1);
        asm volatile("s_waitcnt lgkmcnt(0)" ::: "memory"); // ds_writes visible
        __builtin_amdgcn_sched_barrier(0);
        __builtin_amdgcn_s_barrier();
    }
#pragma unroll
    for (int m = 0; m < 2; ++m)
#pragma unroll
        for (int n2 = 0; n2 < 4; ++n2)
#pragma unroll
            for (int r = 0; r < 4; ++r) {
                const int o = w * 32 + m * 16 + ((l >> 4) << 2) + r;
                const int e = eb + n2 * 16 + (l & 15);
                float v = acc[m][n2][r] + fb[o];
                v = v > 0.f ? v : 0.f;
                YT[(size_t)o * EE + e] = f2bf(v);
            }
}

// ---------- kernel 3: part[kc][n][o] = sum_{e in chunk kc} tgt[n][e] * YT[o][e] ----------
// grid 1024 = 64 mb x 16 kc. LDS 48KB -> 3 blocks/CU. (unchanged — near floor)
__global__ __launch_bounds__(256, 3) void k3_part(const float* __restrict__ tgt,
                                                  const u16* __restrict__ YT,
                                                  float* __restrict__ part) {
    __shared__ __align__(16) char lds[48 * 1024]; // T bufs @0,8K (bf16); Y bufs @16K,32K
    const int bid = (int)blockIdx.x;
    const int mb = bid & 63, kc = bid >> 6;
    const int e0 = kc * 2048;
    const int t = (int)threadIdx.x, w = t >> 6, l = t & 63;
    const int wr = w >> 1, wc = w & 1;
    const int trow = t >> 2, te0 = (t & 3) * 16;  // 64 rows x 4 col-chunks of 16 e

    float4v v0, v1, v2, v3;
    auto loadT = [&](int es) {                    // tgt[mb*64+trow][ec+te0..+15] -> regs
        const float* p = tgt + (size_t)(mb * 64 + trow) * EE + e0 + es * 64 + te0;
        v0 = *(const float4v*)p;
        v1 = *(const float4v*)(p + 4);
        v2 = *(const float4v*)(p + 8);
        v3 = *(const float4v*)(p + 12);
    };
    auto gloadY = [&](int es, int p) {            // Y tile [128 o][64 e] bf16, pre-swz src
        const int ec = e0 + es * 64;
#pragma unroll
        for (int q = 0; q < 4; ++q) {
            const int s = w * 4 + q;
            const int r = s * 8 + (l >> 3);
            const u16* gy = YT + (size_t)r * EE + ec + (((l & 7) ^ (r & 7)) << 3);
            gload16(gy, lds + 16384 + p * 16384 + s * 1024);
        }
    };
    auto writeT = [&](int p) {                    // regs -> T [64 n][64 e] bf16, XOR-swz
        char* buf = lds + p * 8192;
        u32x4 wA, wB;
        wA[0] = cvtpk(v0[0], v0[1]); wA[1] = cvtpk(v0[2], v0[3]);
        wA[2] = cvtpk(v1[0], v1[1]); wA[3] = cvtpk(v1[2], v1[3]);
        wB[0] = cvtpk(v2[0], v2[1]); wB[1] = cvtpk(v2[2], v2[3]);
        wB[2] = cvtpk(v3[0], v3[1]); wB[3] = cvtpk(v3[2], v3[3]);
        *(u32x4*)(buf + trow * 128 + ((te0 * 2) ^ ((trow & 7) << 4))) = wA;
        *(u32x4*)(buf + trow * 128 + ((te0 * 2 + 16) ^ ((trow & 7) << 4))) = wB;
    };

    loadT(0);
    gloadY(0, 0);
    writeT(0);
    __syncthreads();   // prologue only

    float4v acc[2][4] = {};
    for (int es = 0; es < 32; ++es) {
        const int nx = es < 31 ? es + 1 : 31;
        loadT(nx);                                 // 4 reg loads (FIRST)
        gloadY(nx, (es + 1) & 1);                  // 4 gload_lds
        asm volatile("s_waitcnt vmcnt(8)" ::: "memory");   // Y(es) landed (own wave)
        __builtin_amdgcn_sched_barrier(0);
        __builtin_amdgcn_s_barrier();              // all waves' Y(es) landed (cross-wave reads)
        const char* bufT = lds + (es & 1) * 8192;
        const char* bufY = lds + 16384 + (es & 1) * 16384;
        short8v af[2][2], bfr[2][4];
#pragma unroll
        for (int kk = 0; kk < 2; ++kk) {
#pragma unroll
            for (int m = 0; m < 2; ++m)
                af[kk][m] = ldfrag<128>(bufT, wr * 32 + m * 16, kk);
#pragma unroll
            for (int n2 = 0; n2 < 4; ++n2)
                bfr[kk][n2] = ldfrag<128>(bufY, wc * 64 + n2 * 16, kk);
        }
#pragma unroll
        for (int kk = 0; kk < 2; ++kk)
#pragma unroll
            for (int m = 0; m < 2; ++m)
#pragma unroll
                for (int n2 = 0; n2 < 4; ++n2)
                    acc[m][n2] = __builtin_amdgcn_mfma_f32_16x16x32_bf16(
                        af[kk][m], bfr[kk][n2], acc[m][n2], 0, 0, 0);
        asm volatile("s_waitcnt vmcnt(4)" ::: "memory");   // loadT(es+1) regs ready
        __builtin_amdgcn_sched_barrier(0);
        writeT((es + 1) & 1);
        asm volatile("s_waitcnt lgkmcnt(0)" ::: "memory");
        __builtin_amdgcn_sched_barrier(0);
        __builtin_amdgcn_s_barrier();              // T(es+1) published
    }
#pragma unroll
    for (int m = 0; m < 2; ++m)
#pragma unroll
        for (int n2 = 0; n2 < 4; ++n2)
#pragma unroll
            for (int r = 0; r < 4; ++r) {
                const int n = mb * 64 + wr * 32 + m * 16 + ((l >> 4) << 2) + r;
                const int o = wc * 64 + n2 * 16 + (l & 15);
                part[((size_t)kc * NN + n) * DO + o] = acc[m][n2][r];
            }
}

// ---------- kernel 4: out = sum_kc part[kc] ----------
__global__ __launch_bounds__(256) void k4_red(const float* __restrict__ part,
                                              float* __restrict__ out) {
    size_t i = ((size_t)blockIdx.x * 256 + threadIdx.x) * 4;
    float4v s = {0.f, 0.f, 0.f, 0.f};
#pragma unroll
    for (int kc = 0; kc < 16; ++kc)
        s += *(const float4v*)(part + (size_t)kc * NN * DO + i);
    *(float4v*)(out + i) = s;
}

extern "C" void kernel_launch(void* const* d_in, const int* in_sizes, int n_in,
                              void* d_out, int out_size, void* d_ws, size_t ws_size,
                              hipStream_t stream) {
    const float* x   = (const float*)d_in[0];
    const float* src = (const float*)d_in[1];
    const float* tgt = (const float*)d_in[2];
    const float* fw  = (const float*)d_in[3];
    const float* fb  = (const float*)d_in[4];
    float* out = (float*)d_out;

    char* ws = (char*)d_ws;
    u16*   ATB  = (u16*)ws;                                  //  2 MB: [256][4096] bf16
    u16*   YT   = (u16*)(ws + (size_t)2 * 1024 * 1024);      //  8 MB: [128][32768] bf16
    float* PART = (float*)(ws + (size_t)16 * 1024 * 1024);   // 32 MB: [16][4096][128] f32

    k1_ab  <<<64,   256, 0, stream>>>(x, fw, ATB);
    k2_y   <<<512,  256, 0, stream>>>(src, tgt, ATB, fb, YT);
    k3_part<<<1024, 256, 0, stream>>>(tgt, YT, PART);
    k4_red <<<512,  256, 0, stream>>>(PART, out);
}